// Round 5
// baseline (378.860 us; speedup 1.0000x reference)
//
#include <hip/hip_runtime.h>
#include <stdint.h>

typedef __attribute__((ext_vector_type(4))) float  float4v;
typedef __attribute__((ext_vector_type(8))) __bf16 bf16x8;
typedef __attribute__((ext_vector_type(8))) unsigned short ushort8;

#define B_DIM 8192
#define H_DIM 1024
#define O_DIM 1024
#define MSTRIDE (O_DIM * H_DIM)

static __device__ __forceinline__ unsigned short f32_to_bf16(float f) {
  union { float f; unsigned int u; } v; v.f = f;
  unsigned int u = v.u;
  unsigned int r = u + 0x7FFFu + ((u >> 16) & 1u);  // round-to-nearest-even
  return (unsigned short)(r >> 16);
}

static __device__ __forceinline__ bf16x8 pack8(float4v a, float4v b) {
  union { ushort8 u; bf16x8 h; } c;
  c.u[0] = f32_to_bf16(a.x); c.u[1] = f32_to_bf16(a.y);
  c.u[2] = f32_to_bf16(a.z); c.u[3] = f32_to_bf16(a.w);
  c.u[4] = f32_to_bf16(b.x); c.u[5] = f32_to_bf16(b.y);
  c.u[6] = f32_to_bf16(b.z); c.u[7] = f32_to_bf16(b.w);
  return c.h;
}

// ---------------------------------------------------------------------------
// basis [4][H][O] + prj_w [H][O] -> Wt bf16 [5][O][H]  (LDS-tiled transpose)
// grid 1280 x 256
// ---------------------------------------------------------------------------
__global__ void transpose_cast(const float* __restrict__ basis, const float* __restrict__ prjw,
                               unsigned short* __restrict__ Wt) {
  __shared__ __align__(16) unsigned short t[64 * 72];
  int bb = blockIdx.x;
  int m = bb >> 8, panel = bb & 255;
  int o0 = (panel & 15) * 64, h0 = (panel >> 4) * 64;
  const float* src = (m < 4) ? (basis + (size_t)m * H_DIM * O_DIM) : prjw;  // [H][O]
  int tid = threadIdx.x;
  int r  = tid >> 4;
  int c4 = (tid & 15) * 4;
#pragma unroll
  for (int p = 0; p < 4; ++p) {
    int h = r + p * 16;
    float4v v = *(const float4v*)(src + (size_t)(h0 + h) * O_DIM + o0 + c4);
    t[(c4 + 0) * 72 + h] = f32_to_bf16(v.x);
    t[(c4 + 1) * 72 + h] = f32_to_bf16(v.y);
    t[(c4 + 2) * 72 + h] = f32_to_bf16(v.z);
    t[(c4 + 3) * 72 + h] = f32_to_bf16(v.w);
  }
  __syncthreads();
#pragma unroll
  for (int i = 0; i < 2; ++i) {
    int C = i * 256 + tid;
    int o = C >> 3, cc = C & 7;
    ushort8 val = *(const ushort8*)(t + o * 72 + cc * 8);
    *(ushort8*)(Wt + ((size_t)m * O_DIM + o0 + o) * H_DIM + h0 + cc * 8) = val;
  }
}

// ---------------------------------------------------------------------------
// Streaming fused 5-mode GEMM — NO LDS, NO BARRIERS in the K-loop.
//  A fragments read straight from fp32 state (global->VGPR, pack to bf16 in
//  registers); B fragments read straight from bf16 Wt. Each MFMA operand is
//  one contiguous 16B global_load_dwordx4 (fragment layout: lane ln of quad q
//  holds row/col (16t+ln), k = q*8..q*8+7). The wave scheduler + fine vmcnt
//  hide L2 latency across 2 waves/SIMD — the R3/R4 barrier drain (54% stall)
//  and the LDS bandwidth co-limit (reads+writes > MFMA window) both vanish.
//  Tile 128(B) x 64(O); waves 2x2 of 64x32; acc[5][4][2] = 160 VGPRs.
//  Epilogue: per-row coeff combine -> LDS repack -> float4 full-line stores
//  (R3-proven: WRITE_SIZE == 32 MB exact).
// ---------------------------------------------------------------------------
__global__ __launch_bounds__(256, 2)
void gemm_fused(const float* __restrict__ state,
                const unsigned short* __restrict__ Wt,
                const float* __restrict__ se, const float* __restrict__ curv,
                const float* __restrict__ gw, const float* __restrict__ gb,
                const float* __restrict__ prjb,
                float* __restrict__ out) {
  __shared__ __align__(16) unsigned char smem[37376];
  float* fbuf = (float*)smem;            // 128 x 68 fp32 = 34816 B (epilogue)
  float* scf  = (float*)(smem + 34816);  // 5 x 128 fp32

  const int tid  = threadIdx.x;
  const int lane = tid & 63;
  const int wave = tid >> 6;
  const int row0 = blockIdx.x * 128;
  const int col0 = blockIdx.y * 64;
  const int wrow = (wave >> 1) * 64;   // 0 or 64
  const int wcol = (wave & 1) * 32;    // 0 or 32
  const int q  = lane >> 4;
  const int ln = lane & 15;

  // ---- fused coeff prep for this block's 128 rows (read in epilogue only;
  //      the pre-epilogue __syncthreads orders it)
  if (tid < 128) {
    int b = row0 + tid;
    float s = se[b];
    float l0 = fmaf(s, gw[0], gb[0]);
    float l1 = fmaf(s, gw[1], gb[1]);
    float l2 = fmaf(s, gw[2], gb[2]);
    float l3 = fmaf(s, gw[3], gb[3]);
    float mx = fmaxf(fmaxf(l0, l1), fmaxf(l2, l3));
    float e0 = __expf(l0 - mx), e1 = __expf(l1 - mx);
    float e2 = __expf(l2 - mx), e3 = __expf(l3 - mx);
    float mix = 1.0f / (1.0f + __expf(-curv[b]));
    float inv = mix / (e0 + e1 + e2 + e3);
    scf[0 * 128 + tid] = e0 * inv;
    scf[1 * 128 + tid] = e1 * inv;
    scf[2 * 128 + tid] = e2 * inv;
    scf[3 * 128 + tid] = e3 * inv;
    scf[4 * 128 + tid] = 1.0f - mix;
  }

  // ---- per-lane streaming base pointers
  const float* aptr[4];
#pragma unroll
  for (int t = 0; t < 4; ++t)
    aptr[t] = state + (size_t)(row0 + wrow + t * 16 + ln) * H_DIM + q * 8;
  const unsigned short* bptr0 = Wt + (size_t)(col0 + wcol + ln)      * H_DIM + q * 8;
  const unsigned short* bptr1 = Wt + (size_t)(col0 + wcol + 16 + ln) * H_DIM + q * 8;

  float4v acc[5][4][2];
#pragma unroll
  for (int m = 0; m < 5; ++m)
#pragma unroll
    for (int i = 0; i < 4; ++i)
#pragma unroll
      for (int j = 0; j < 2; ++j)
        acc[m][i][j] = (float4v){0.f, 0.f, 0.f, 0.f};

#pragma unroll 2
  for (int s = 0; s < 32; ++s) {
    const int k = s * 32;
    bf16x8 af[4];
#pragma unroll
    for (int t = 0; t < 4; ++t) {
      float4v u0 = *(const float4v*)(aptr[t] + k);
      float4v u1 = *(const float4v*)(aptr[t] + k + 4);
      af[t] = pack8(u0, u1);
    }
#pragma unroll
    for (int m = 0; m < 5; ++m) {
      bf16x8 b0 = *(const bf16x8*)(bptr0 + (size_t)m * MSTRIDE + k);
      bf16x8 b1 = *(const bf16x8*)(bptr1 + (size_t)m * MSTRIDE + k);
#pragma unroll
      for (int ti = 0; ti < 4; ++ti) {
        acc[m][ti][0] = __builtin_amdgcn_mfma_f32_16x16x32_bf16(af[ti], b0, acc[m][ti][0], 0, 0, 0);
        acc[m][ti][1] = __builtin_amdgcn_mfma_f32_16x16x32_bf16(af[ti], b1, acc[m][ti][1], 0, 0, 0);
      }
    }
  }

  // ---- epilogue: mode-combine -> LDS repack (fp32, pitch 68) -> float4 stores
  __syncthreads();  // scf visible; fbuf region free (no other LDS use)
#pragma unroll
  for (int ti = 0; ti < 4; ++ti) {
    int rl = wrow + ti * 16 + q * 4;
#pragma unroll
    for (int tj = 0; tj < 2; ++tj) {
      int cc = wcol + tj * 16 + ln;
#pragma unroll
      for (int r = 0; r < 4; ++r) {
        float v = 0.f;
#pragma unroll
        for (int m = 0; m < 5; ++m)
          v += scf[m * 128 + rl + r] * acc[m][ti][tj][r];
        fbuf[(rl + r) * 68 + cc] = v;
      }
    }
  }
  __syncthreads();
#pragma unroll
  for (int i = 0; i < 8; ++i) {
    int L = i * 256 + tid;          // 2048 float4s = 128 rows x 16
    int row = L >> 4, c4 = L & 15;
    float4v v = *(const float4v*)(fbuf + row * 68 + c4 * 4);
    float cb = scf[4 * 128 + row];
    float4v pb = *(const float4v*)(prjb + col0 + c4 * 4);
    v += cb * pb;
    *(float4v*)(out + (size_t)(row0 + row) * O_DIM + col0 + c4 * 4) = v;
  }
}

// ---------------------------------------------------------------------------
extern "C" void kernel_launch(void* const* d_in, const int* in_sizes, int n_in,
                              void* d_out, int out_size, void* d_ws, size_t ws_size,
                              hipStream_t stream) {
  const float* state = (const float*)d_in[0];
  const float* se    = (const float*)d_in[1];
  const float* curv  = (const float*)d_in[2];
  const float* basis = (const float*)d_in[3];
  const float* gw    = (const float*)d_in[4];
  const float* gb    = (const float*)d_in[5];
  const float* prjw  = (const float*)d_in[6];
  const float* prjb  = (const float*)d_in[7];
  float* out = (float*)d_out;

  unsigned short* Wt = (unsigned short*)d_ws;  // 10 MB bf16 [5][O][H]

  transpose_cast<<<1280, 256, 0, stream>>>(basis, prjw, Wt);
  dim3 gg(B_DIM / 128, O_DIM / 64);
  gemm_fused<<<gg, 256, 0, stream>>>(state, Wt, se, curv, gw, gb, prjb, out);
}

// Round 6
// 205.644 us; speedup vs baseline: 1.8423x; 1.8423x over previous
//
#include <hip/hip_runtime.h>
#include <stdint.h>

typedef __attribute__((ext_vector_type(4))) float  float4v;
typedef __attribute__((ext_vector_type(8))) __bf16 bf16x8;
typedef __attribute__((ext_vector_type(8))) unsigned short ushort8;

#define B_DIM 8192
#define H_DIM 1024
#define O_DIM 1024

static __device__ __forceinline__ unsigned short f32_to_bf16(float f) {
  union { float f; unsigned int u; } v; v.f = f;
  unsigned int u = v.u;
  unsigned int r = u + 0x7FFFu + ((u >> 16) & 1u);  // round-to-nearest-even
  return (unsigned short)(r >> 16);
}

// ---------------------------------------------------------------------------
// prep_inputs (R4-verified): weight transpose + state cast in one launch.
//  blocks [0,1280): basis[4][H][O] + prj_w[H][O] -> Wt bf16 [5][O][H]
//  blocks [1280,5376): state fp32 [B][H] -> Abf bf16 [B][H]
// ---------------------------------------------------------------------------
__global__ void prep_inputs(const float* __restrict__ state,
                            const float* __restrict__ basis,
                            const float* __restrict__ prjw,
                            unsigned short* __restrict__ Abf,
                            unsigned short* __restrict__ Wt) {
  __shared__ __align__(16) unsigned short t[64 * 72];
  int bb = blockIdx.x;
  int tid = threadIdx.x;
  if (bb < 1280) {
    int m = bb >> 8, panel = bb & 255;
    int o0 = (panel & 15) * 64, h0 = (panel >> 4) * 64;
    const float* src = (m < 4) ? (basis + (size_t)m * H_DIM * O_DIM) : prjw;  // [H][O]
    int r  = tid >> 4;
    int c4 = (tid & 15) * 4;
#pragma unroll
    for (int p = 0; p < 4; ++p) {
      int h = r + p * 16;
      float4v v = *(const float4v*)(src + (size_t)(h0 + h) * O_DIM + o0 + c4);
      t[(c4 + 0) * 72 + h] = f32_to_bf16(v.x);
      t[(c4 + 1) * 72 + h] = f32_to_bf16(v.y);
      t[(c4 + 2) * 72 + h] = f32_to_bf16(v.z);
      t[(c4 + 3) * 72 + h] = f32_to_bf16(v.w);
    }
    __syncthreads();
#pragma unroll
    for (int i = 0; i < 2; ++i) {
      int C = i * 256 + tid;
      int o = C >> 3, cc = C & 7;
      ushort8 val = *(const ushort8*)(t + o * 72 + cc * 8);
      *(ushort8*)(Wt + ((size_t)m * O_DIM + o0 + o) * H_DIM + h0 + cc * 8) = val;
    }
  } else {
    int i = (bb - 1280) * 256 + tid;  // 8 elems per thread
    float4v v0 = ((const float4v*)state)[i * 2];
    float4v v1 = ((const float4v*)state)[i * 2 + 1];
    ushort8 o;
    o[0] = f32_to_bf16(v0.x); o[1] = f32_to_bf16(v0.y);
    o[2] = f32_to_bf16(v0.z); o[3] = f32_to_bf16(v0.w);
    o[4] = f32_to_bf16(v1.x); o[5] = f32_to_bf16(v1.y);
    o[6] = f32_to_bf16(v1.z); o[7] = f32_to_bf16(v1.w);
    ((ushort8*)Abf)[i] = o;
  }
}

// ---------------------------------------------------------------------------
// Fused 5-mode GEMM with MODE-FOLD accumulation.
//  out[b,o] = sum_m c_m[b] * (A . W_m)[b,o] ; per phase/mode: tmp = mfma(a,b,0),
//  oacc += creg[m] * tmp  (coeffs hoisted to registers). Accumulator state
//  drops 160 -> 32 floats => ~190 regs/wave => 2 waves/SIMD, 2 blocks/CU
//  resident (R3/R4 were register-bound to 1 block/CU => no drain cover).
//  Tile 128(B) x 64(O); waves 2x2 (64x32); BK=32 double-buffer (56 KB):
//  issue s+1 -> compute s -> barrier. Residual drain of each block is covered
//  by the other resident block's compute window.
// ---------------------------------------------------------------------------
__global__ __launch_bounds__(256, 2)
void gemm_fused(const unsigned short* __restrict__ A,
                const unsigned short* __restrict__ Wt,
                const float* __restrict__ se, const float* __restrict__ curv,
                const float* __restrict__ gw, const float* __restrict__ gb,
                const float* __restrict__ prjb,
                float* __restrict__ out) {
  __shared__ __align__(16) unsigned char smem[59904];
  // stage buf (s&1) at (s&1)*28672: [A 128x32 bf16 = 8192B][B 5 x 64x32 = 20480B]
  float* scf = (float*)(smem + 57344);  // 5 x 128 fp32

  const int tid  = threadIdx.x;
  const int lane = tid & 63;
  const int wave = tid >> 6;
  const int row0 = blockIdx.x * 128;
  const int col0 = blockIdx.y * 64;
  const int wrow = (wave >> 1) * 64;   // 0 or 64
  const int wcol = (wave & 1) * 32;    // 0 or 32
  const int q  = lane >> 4;
  const int ln = lane & 15;

  // ---- fused coeff prep for this block's 128 rows
  if (tid < 128) {
    int b = row0 + tid;
    float s = se[b];
    float l0 = fmaf(s, gw[0], gb[0]);
    float l1 = fmaf(s, gw[1], gb[1]);
    float l2 = fmaf(s, gw[2], gb[2]);
    float l3 = fmaf(s, gw[3], gb[3]);
    float mx = fmaxf(fmaxf(l0, l1), fmaxf(l2, l3));
    float e0 = __expf(l0 - mx), e1 = __expf(l1 - mx);
    float e2 = __expf(l2 - mx), e3 = __expf(l3 - mx);
    float mix = 1.0f / (1.0f + __expf(-curv[b]));
    float inv = mix / (e0 + e1 + e2 + e3);
    scf[0 * 128 + tid] = e0 * inv;
    scf[1 * 128 + tid] = e1 * inv;
    scf[2 * 128 + tid] = e2 * inv;
    scf[3 * 128 + tid] = e3 * inv;
    scf[4 * 128 + tid] = 1.0f - mix;
  }

  // ---- staging descriptors (R4-verified; 16B chunks, rows = 32 elems = 4
  //      chunks, fetch-side swizzle g = pos ^ ((row>>1)&3))
  const unsigned short* gA[2];
  unsigned int ldsA[2];
#pragma unroll
  for (int j = 0; j < 2; ++j) {
    int C = (wave * 2 + j) * 64 + lane;     // 0..511
    int row = C >> 2, pos = C & 3;
    int g = pos ^ ((row >> 1) & 3);
    gA[j] = A + (size_t)(row0 + row) * H_DIM + g * 8;
    ldsA[j] = (wave * 2 + j) * 1024;        // wave-uniform base (HW adds lane*16)
  }
  const unsigned short* gB[5];
  unsigned int ldsBbase = 8192 + wave * 1024;
  {
    int C = wave * 64 + lane;               // 0..255
    int row = C >> 2, pos = C & 3;
    int g = pos ^ ((row >> 1) & 3);
#pragma unroll
    for (int m = 0; m < 5; ++m)
      gB[m] = Wt + (size_t)m * O_DIM * H_DIM + (size_t)(col0 + row) * H_DIM + g * 8;
  }

#define ISSUE_STAGE(s)                                                          \
  do {                                                                          \
    unsigned char* _base = smem + ((s) & 1) * 28672;                            \
    const int _k = (s) * 32;                                                    \
    _Pragma("unroll")                                                           \
    for (int _j = 0; _j < 2; ++_j)                                              \
      __builtin_amdgcn_global_load_lds(                                         \
          (const __attribute__((address_space(1))) void*)(gA[_j] + _k),         \
          (__attribute__((address_space(3))) void*)(_base + ldsA[_j]), 16, 0, 0);\
    _Pragma("unroll")                                                           \
    for (int _m = 0; _m < 5; ++_m)                                              \
      __builtin_amdgcn_global_load_lds(                                         \
          (const __attribute__((address_space(1))) void*)(gB[_m] + _k),         \
          (__attribute__((address_space(3))) void*)(_base + ldsBbase + _m * 4096),\
          16, 0, 0);                                                            \
  } while (0)

  float4v oacc[4][2];
#pragma unroll
  for (int i = 0; i < 4; ++i)
#pragma unroll
    for (int j = 0; j < 2; ++j)
      oacc[i][j] = (float4v){0.f, 0.f, 0.f, 0.f};

  ISSUE_STAGE(0);
  __syncthreads();  // stage 0 landed; scf visible

  // ---- hoist per-mode per-row coefficients into registers (C/D row = q*4+reg)
  float4v creg[5][4];
#pragma unroll
  for (int m = 0; m < 5; ++m)
#pragma unroll
    for (int ti = 0; ti < 4; ++ti)
      creg[m][ti] = *(const float4v*)(scf + m * 128 + wrow + ti * 16 + q * 4);

  const float4v zf = (float4v){0.f, 0.f, 0.f, 0.f};

#pragma unroll 2
  for (int s = 0; s < 32; ++s) {
    if (s < 31) ISSUE_STAGE(s + 1);   // prefetch into the other buffer
    {
      const unsigned short* sAb = (const unsigned short*)(smem + (s & 1) * 28672);
      const unsigned short* sBb = sAb + 4096;  // +8192 bytes
      bf16x8 af[4];
#pragma unroll
      for (int t = 0; t < 4; ++t) {
        int ra = wrow + t * 16 + ln;
        int ps = q ^ ((ra >> 1) & 3);
        af[t] = *(const bf16x8*)(sAb + ra * 32 + ps * 8);
      }
#pragma unroll
      for (int m = 0; m < 5; ++m) {
        int rb0 = wcol + ln;
        int p0  = q ^ ((rb0 >> 1) & 3);
        bf16x8 b0 = *(const bf16x8*)(sBb + m * 2048 + rb0 * 32 + p0 * 8);
        int rb1 = wcol + 16 + ln;
        int p1  = q ^ ((rb1 >> 1) & 3);
        bf16x8 b1 = *(const bf16x8*)(sBb + m * 2048 + rb1 * 32 + p1 * 8);
#pragma unroll
        for (int ti = 0; ti < 4; ++ti) {
          float4v t0 = __builtin_amdgcn_mfma_f32_16x16x32_bf16(af[ti], b0, zf, 0, 0, 0);
          oacc[ti][0] += creg[m][ti] * t0;
          float4v t1 = __builtin_amdgcn_mfma_f32_16x16x32_bf16(af[ti], b1, zf, 0, 0, 0);
          oacc[ti][1] += creg[m][ti] * t1;
        }
      }
    }
    __syncthreads();  // all waves done with buf s; drains s+1 loads
  }
#undef ISSUE_STAGE

  // ---- epilogue: LDS repack (fp32, pitch 68) -> float4 full-line stores
  float* fbuf = (float*)smem;  // 128 x 68 fp32 = 34816 B (scf at 57344 safe)
#pragma unroll
  for (int ti = 0; ti < 4; ++ti) {
    int rl = wrow + ti * 16 + q * 4;
#pragma unroll
    for (int tj = 0; tj < 2; ++tj) {
      int cc = wcol + tj * 16 + ln;
#pragma unroll
      for (int r = 0; r < 4; ++r)
        fbuf[(rl + r) * 68 + cc] = oacc[ti][tj][r];
    }
  }
  __syncthreads();
#pragma unroll
  for (int i = 0; i < 8; ++i) {
    int L = i * 256 + tid;          // 2048 float4s = 128 rows x 16
    int row = L >> 4, c4 = L & 15;
    float4v v = *(const float4v*)(fbuf + row * 68 + c4 * 4);
    float cb = scf[4 * 128 + row];
    float4v pb = *(const float4v*)(prjb + col0 + c4 * 4);
    v += cb * pb;
    *(float4v*)(out + (size_t)(row0 + row) * O_DIM + col0 + c4 * 4) = v;
  }
}

// ---------------------------------------------------------------------------
extern "C" void kernel_launch(void* const* d_in, const int* in_sizes, int n_in,
                              void* d_out, int out_size, void* d_ws, size_t ws_size,
                              hipStream_t stream) {
  const float* state = (const float*)d_in[0];
  const float* se    = (const float*)d_in[1];
  const float* curv  = (const float*)d_in[2];
  const float* basis = (const float*)d_in[3];
  const float* gw    = (const float*)d_in[4];
  const float* gb    = (const float*)d_in[5];
  const float* prjw  = (const float*)d_in[6];
  const float* prjb  = (const float*)d_in[7];
  float* out = (float*)d_out;

  char* ws = (char*)d_ws;
  unsigned short* Abf = (unsigned short*)ws;                               // 16 MB
  unsigned short* Wt  = (unsigned short*)(ws + (size_t)16 * 1024 * 1024);  // 10 MB

  prep_inputs<<<5376, 256, 0, stream>>>(state, basis, prjw, Abf, Wt);
  dim3 gg(B_DIM / 128, O_DIM / 64);
  gemm_fused<<<gg, 256, 0, stream>>>(Abf, Wt, se, curv, gw, gb, prjb, out);
}